// Round 2
// baseline (4597.242 us; speedup 1.0000x reference)
//
#include <hip/hip_runtime.h>
#include <hip/hip_bf16.h>

typedef unsigned short ushort_t;

// ---------------- problem constants ----------------
constexpr int NU = 100000, N1 = 60000, N2 = 60000;
constexpr int E = 2000000;
constexpr int TOTN = 2 * NU + N1 + N2;  // deg/norm layout: [du1|di1|du2|di2]

__device__ __forceinline__ ushort_t f2bf(float f) {
  unsigned u = __float_as_uint(f);
  u = u + 0x7fffu + ((u >> 16) & 1u);   // round-to-nearest-even
  return (ushort_t)(u >> 16);
}

// ---------------- degree count ----------------
__global__ __launch_bounds__(256) void k_count(const int* __restrict__ s1,
                                               const int* __restrict__ d1,
                                               const int* __restrict__ s2,
                                               const int* __restrict__ d2,
                                               int* __restrict__ deg) {
  int e = blockIdx.x * 256 + threadIdx.x;
  if (e >= E) return;
  atomicAdd(&deg[s1[e]], 1);
  atomicAdd(&deg[NU + d1[e]], 1);
  atomicAdd(&deg[NU + N1 + s2[e]], 1);
  atomicAdd(&deg[2 * NU + N1 + d2[e]], 1);
}

// ---------------- normalizers ----------------
__global__ __launch_bounds__(256) void k_norm(const int* __restrict__ deg,
                                              float* __restrict__ nrm) {
  int i = blockIdx.x * 256 + threadIdx.x;
  if (i >= TOTN) return;
  int d = deg[i];
  nrm[i] = rsqrtf((float)(d > 1 ? d : 1));
}

// ---------------- batched exclusive prefix scan (4 segments) ----------------
__global__ __launch_bounds__(256) void k_scan(const int* __restrict__ deg,
                                              int* __restrict__ off,
                                              int* __restrict__ cur) {
  __shared__ int wsum[4];
  int seg = blockIdx.x;
  int baseIn, n, baseOut;
  if (seg == 0)      { baseIn = 0;            n = NU; baseOut = 0; }
  else if (seg == 1) { baseIn = NU;           n = N1; baseOut = NU + 1; }
  else if (seg == 2) { baseIn = NU + N1;      n = NU; baseOut = NU + N1 + 2; }
  else               { baseIn = 2 * NU + N1;  n = N2; baseOut = 2 * NU + N1 + 3; }
  const int* in = deg + baseIn;
  int* out = off + baseOut;
  int* curp = cur + baseIn;

  constexpr int ITEMS = 16;            // 256*16 = 4096 per chunk
  int t = threadIdx.x, lane = t & 63, wid = t >> 6;
  int carry = 0;
  for (int base = 0; base < n; base += 256 * ITEMS) {
    int vals[ITEMS];
    int lsum = 0;
    int i0 = base + t * ITEMS;
#pragma unroll
    for (int j = 0; j < ITEMS; ++j) {
      int i = i0 + j;
      int v = (i < n) ? in[i] : 0;
      vals[j] = v;
      lsum += v;
    }
    int incl = lsum;
#pragma unroll
    for (int d = 1; d < 64; d <<= 1) {
      int x = __shfl_up(incl, d, 64);
      if (lane >= d) incl += x;
    }
    if (lane == 63) wsum[wid] = incl;
    __syncthreads();
    int woff = 0;
    for (int w = 0; w < wid; ++w) woff += wsum[w];
    int chunkTotal = wsum[0] + wsum[1] + wsum[2] + wsum[3];
    int excl = carry + woff + (incl - lsum);
#pragma unroll
    for (int j = 0; j < ITEMS; ++j) {
      int i = i0 + j;
      if (i < n) { out[i] = excl; curp[i] = excl; }
      excl += vals[j];
    }
    carry += chunkTotal;
    __syncthreads();
  }
  if (t == 0) out[n] = carry;
}

// ---------------- adjacency fill ----------------
__global__ __launch_bounds__(256) void k_fill(const int* __restrict__ s1,
                                              const int* __restrict__ d1,
                                              const int* __restrict__ s2,
                                              const int* __restrict__ d2,
                                              int* __restrict__ cur,
                                              int* __restrict__ a_s1,
                                              int* __restrict__ a_d1,
                                              int* __restrict__ a_s2,
                                              int* __restrict__ a_d2) {
  int e = blockIdx.x * 256 + threadIdx.x;
  if (e >= E) return;
  int a = s1[e], b = d1[e];
  a_s1[atomicAdd(&cur[a], 1)] = b;
  a_d1[atomicAdd(&cur[NU + b], 1)] = a;
  int c = s2[e], d = d2[e];
  a_s2[atomicAdd(&cur[NU + N1 + c], 1)] = d;
  a_d2[atomicAdd(&cur[2 * NU + N1 + d], 1)] = c;
}

// ---------------- dense GEMM: C[M][N] = A[M][K] @ W[K][N] ----------------
// BF16OUT: C is bf16 (ushort), else fp32. 32KB max LDS (two-stage K).
template <int K, int N, bool BF16OUT>
__global__ __launch_bounds__(256) void k_gemm(const float* __restrict__ A,
                                              const float* __restrict__ W,
                                              void* __restrict__ Cv, int M) {
  constexpr int CG = N / 8;        // colgroups
  constexpr int RG = 256 / CG;     // rowgroups
  constexpr int RPB = RG * 4;      // rows per block
  __shared__ float sW[64 * N];
  int cg = threadIdx.x % CG, rg = threadIdx.x / CG;
  int r0 = blockIdx.x * RPB + rg * 4;
  int c0 = cg * 8;
  float acc[4][8] = {};
  for (int k0 = 0; k0 < K; k0 += 64) {
    if (k0) __syncthreads();
    for (int i = threadIdx.x * 4; i < 64 * N; i += 256 * 4)
      *(float4*)&sW[i] = *(const float4*)&W[k0 * N + i];
    __syncthreads();
    for (int k = 0; k < 64; k += 4) {
      float4 a[4];
#pragma unroll
      for (int r = 0; r < 4; ++r) {
        int rr = r0 + r; if (rr > M - 1) rr = M - 1;
        a[r] = *(const float4*)&A[(size_t)rr * K + k0 + k];
      }
#pragma unroll
      for (int kk = 0; kk < 4; ++kk) {
        float w[8];
        *(float4*)&w[0] = *(const float4*)&sW[(k + kk) * N + c0];
        *(float4*)&w[4] = *(const float4*)&sW[(k + kk) * N + c0 + 4];
#pragma unroll
        for (int r = 0; r < 4; ++r) {
          float av = kk == 0 ? a[r].x : kk == 1 ? a[r].y : kk == 2 ? a[r].z : a[r].w;
#pragma unroll
          for (int j = 0; j < 8; ++j) acc[r][j] += av * w[j];
        }
      }
    }
  }
#pragma unroll
  for (int r = 0; r < 4; ++r) {
    int rr = r0 + r;
    if (rr >= M) break;
    if constexpr (BF16OUT) {
      ushort_t* C = (ushort_t*)Cv;
      union { ushort_t h[8]; int4 v; } u_;
#pragma unroll
      for (int j = 0; j < 8; ++j) u_.h[j] = f2bf(acc[r][j]);
      *(int4*)&C[(size_t)rr * N + c0] = u_.v;
    } else {
      float* C = (float*)Cv;
#pragma unroll
      for (int j = 0; j < 8; j += 4)
        *(float4*)&C[(size_t)rr * N + c0 + j] = *(float4*)&acc[r][j];
    }
  }
}

// ---------------- CSR gather from bf16 z ----------------
// out[v*D + c] (=old+) ndst[v] * sum_{s in adj[off[v]..]} nsrc[s]*z[s*D+c] (+bias)
template <int D, bool ACCUM, bool RELU>
__global__ __launch_bounds__(256) void k_gather(const ushort_t* __restrict__ z,
                                                const int* __restrict__ off,
                                                const int* __restrict__ adj,
                                                const float* __restrict__ nsrc,
                                                const float* __restrict__ ndst,
                                                const float* __restrict__ bias,
                                                const float* __restrict__ bias2,
                                                float* __restrict__ out, int nv) {
  constexpr int LPN = D / 2;        // lanes per node (each lane: 2 channels)
  constexpr int NPB = 256 / LPN;    // nodes per block
  int t = threadIdx.x;
  int slot = t / LPN, l = t % LPN;
  int v = blockIdx.x * NPB + slot;
  if (v >= nv) return;
  int e0 = off[v], e1 = off[v + 1];
  float a0 = 0.f, a1 = 0.f;
  for (int e = e0; e < e1; ++e) {
    int s = adj[e];
    float w = nsrc[s];
    unsigned pk = *(const unsigned*)&z[(size_t)s * D + 2 * l];
    a0 += w * __uint_as_float(pk << 16);
    a1 += w * __uint_as_float(pk & 0xffff0000u);
  }
  float nd = ndst[v];
  float r0, r1;
  size_t o = (size_t)v * D + 2 * l;
  if constexpr (ACCUM) {
    float2 old = *(const float2*)&out[o];
    r0 = old.x + nd * a0;
    r1 = old.y + nd * a1;
  } else {
    float b0 = bias[2 * l], b1 = bias[2 * l + 1];
    if (bias2) { b0 += bias2[2 * l]; b1 += bias2[2 * l + 1]; }
    r0 = nd * a0 + b0;
    r1 = nd * a1 + b1;
  }
  if constexpr (RELU) { r0 = fmaxf(r0, 0.f); r1 = fmaxf(r1, 0.f); }
  float2 res; res.x = r0; res.y = r1;
  *(float2*)&out[o] = res;
}

// ---------------- edge scoring: out[e] = dot(u[src[e]], it[dst[e]]) over 64 ----------------
__global__ __launch_bounds__(256) void k_score(const float* __restrict__ u,
                                               const float* __restrict__ it,
                                               const int* __restrict__ src,
                                               const int* __restrict__ dst,
                                               float* __restrict__ out, int ne) {
  int e = blockIdx.x * 256 + threadIdx.x;
  if (e >= ne) return;
  const float4* a = (const float4*)(u + (size_t)src[e] * 64);
  const float4* b = (const float4*)(it + (size_t)dst[e] * 64);
  float s = 0.f;
#pragma unroll
  for (int j = 0; j < 16; ++j) {
    float4 x = a[j], y = b[j];
    s += x.x * y.x + x.y * y.y + x.z * y.z + x.w * y.w;
  }
  out[e] = s;
}

// ---------------- host launch ----------------
extern "C" void kernel_launch(void* const* d_in, const int* in_sizes, int n_in,
                              void* d_out, int out_size, void* d_ws, size_t ws_size,
                              hipStream_t stream) {
  const float* emb_user = (const float*)d_in[0];
  const float* emb_d1   = (const float*)d_in[1];
  const float* emb_d2   = (const float*)d_in[2];
  const float* W_in     = (const float*)d_in[3];
  const float* b_in     = (const float*)d_in[4];
  const float* W_hid    = (const float*)d_in[5];
  const float* b_hid    = (const float*)d_in[6];
  const float* W_out    = (const float*)d_in[7];
  const float* b_out    = (const float*)d_in[8];
  const float* Wp_d1    = (const float*)d_in[9];
  const float* Wp_d2    = (const float*)d_in[10];
  const int* src_d1     = (const int*)d_in[11];
  const int* dst_d1     = (const int*)d_in[12];
  const int* src_d2     = (const int*)d_in[13];
  const int* dst_d2     = (const int*)d_in[14];
  float* out = (float*)d_out;

  char* p = (char*)d_ws;
  auto alloc = [&](size_t bytes) {
    void* r = (void*)p;
    p += (bytes + 15) & ~(size_t)15;
    return r;
  };
  float* bufU[2] = {(float*)alloc((size_t)NU * 128 * 4), (float*)alloc((size_t)NU * 128 * 4)};
  float* bufI1 = (float*)alloc((size_t)N1 * 128 * 4);
  float* bufI2 = (float*)alloc((size_t)N2 * 128 * 4);
  ushort_t* m = (ushort_t*)alloc((size_t)NU * 128 * 2);  // bf16 GEMM staging
  float* nrm = (float*)alloc((size_t)TOTN * 4);
  int* deg = (int*)alloc((size_t)TOTN * 4);
  int* off = (int*)alloc((size_t)(TOTN + 4) * 4);
  int* cur = (int*)alloc((size_t)TOTN * 4);
  int* adj_s1 = (int*)alloc((size_t)E * 4);
  int* adj_d1 = (int*)alloc((size_t)E * 4);
  int* adj_s2 = (int*)alloc((size_t)E * 4);
  int* adj_d2 = (int*)alloc((size_t)E * 4);

  // ws guard: if scratch is too small, do nothing (test fails with absmax =
  // ref-absmax instead of a GPU fault -> diagnosable next round).
  if ((size_t)(p - (char*)d_ws) > ws_size) return;

  const float* nu1 = nrm;
  const float* ni1 = nrm + NU;
  const float* nu2 = nrm + NU + N1;
  const float* ni2 = nrm + 2 * NU + N1;
  const int* off_u1 = off;
  const int* off_i1 = off + NU + 1;
  const int* off_u2 = off + NU + N1 + 2;
  const int* off_i2 = off + 2 * NU + N1 + 3;

  int gE = (E + 255) / 256;

  // ---- graph preprocessing ----
  hipMemsetAsync(deg, 0, (size_t)TOTN * 4, stream);
  k_count<<<gE, 256, 0, stream>>>(src_d1, dst_d1, src_d2, dst_d2, deg);
  k_norm<<<(TOTN + 255) / 256, 256, 0, stream>>>(deg, nrm);
  k_scan<<<4, 256, 0, stream>>>(deg, off, cur);
  k_fill<<<gE, 256, 0, stream>>>(src_d1, dst_d1, src_d2, dst_d2, cur,
                                 adj_s1, adj_d1, adj_s2, adj_d2);

  // ---- 3 GraphConv layers ----
  // Order per layer: (1) u-side from I1 then I2 (old I1/I2 die after their
  // GEMMs), (2) i-sides from U written IN-PLACE, (3) U ping-pong.
  const float* U = emb_user;
  const float* I1 = emb_d1;
  const float* I2 = emb_d2;
  for (int L = 0; L < 3; ++L) {
    const float* W = L == 0 ? W_in : L == 1 ? W_hid : W_out;
    const float* B = L == 0 ? b_in : L == 1 ? b_hid : b_out;
    float* uNew = bufU[L % 2];
    if (L < 2) {
      constexpr int Nc = 128;
      k_gemm<128, Nc, true><<<(N1 + 63) / 64, 256, 0, stream>>>(I1, W + 1 * 128 * Nc, m, N1);
      k_gather<Nc, false, false><<<(NU + 3) / 4, 256, 0, stream>>>(
          m, off_u1, adj_s1, ni1, nu1, B + 1 * Nc, B + 3 * Nc, uNew, NU);
      k_gemm<128, Nc, true><<<(N2 + 63) / 64, 256, 0, stream>>>(I2, W + 3 * 128 * Nc, m, N2);
      k_gather<Nc, true, true><<<(NU + 3) / 4, 256, 0, stream>>>(
          m, off_u2, adj_s2, ni2, nu2, nullptr, nullptr, uNew, NU);
      k_gemm<128, Nc, true><<<(NU + 63) / 64, 256, 0, stream>>>(U, W + 0 * 128 * Nc, m, NU);
      k_gather<Nc, false, true><<<(N1 + 3) / 4, 256, 0, stream>>>(
          m, off_i1, adj_d1, nu1, ni1, B + 0 * Nc, nullptr, bufI1, N1);
      k_gemm<128, Nc, true><<<(NU + 63) / 64, 256, 0, stream>>>(U, W + 2 * 128 * Nc, m, NU);
      k_gather<Nc, false, true><<<(N2 + 3) / 4, 256, 0, stream>>>(
          m, off_i2, adj_d2, nu2, ni2, B + 2 * Nc, nullptr, bufI2, N2);
    } else {
      constexpr int Nc = 64;
      k_gemm<128, Nc, true><<<(N1 + 127) / 128, 256, 0, stream>>>(I1, W + 1 * 128 * Nc, m, N1);
      k_gather<Nc, false, false><<<(NU + 7) / 8, 256, 0, stream>>>(
          m, off_u1, adj_s1, ni1, nu1, B + 1 * Nc, B + 3 * Nc, uNew, NU);
      k_gemm<128, Nc, true><<<(N2 + 127) / 128, 256, 0, stream>>>(I2, W + 3 * 128 * Nc, m, N2);
      k_gather<Nc, true, false><<<(NU + 7) / 8, 256, 0, stream>>>(
          m, off_u2, adj_s2, ni2, nu2, nullptr, nullptr, uNew, NU);
      k_gemm<128, Nc, true><<<(NU + 63) / 64, 256, 0, stream>>>(U, W + 0 * 128 * Nc, m, NU);
      k_gather<Nc, false, false><<<(N1 + 7) / 8, 256, 0, stream>>>(
          m, off_i1, adj_d1, nu1, ni1, B + 0 * Nc, nullptr, bufI1, N1);
      k_gemm<128, Nc, true><<<(NU + 63) / 64, 256, 0, stream>>>(U, W + 2 * 128 * Nc, m, NU);
      k_gather<Nc, false, false><<<(N2 + 7) / 8, 256, 0, stream>>>(
          m, off_i2, adj_d2, nu2, ni2, B + 2 * Nc, nullptr, bufI2, N2);
    }
    U = uNew;
    I1 = bufI1;
    I2 = bufI2;
  }

  // ---- projections + scoring ----
  // After layer 2, U = bufU[0]; bufU[1] is free -> holds u1|u2 (fp32, 64-wide).
  float* u1 = bufU[1];
  float* u2 = bufU[1] + (size_t)NU * 64;
  k_gemm<64, 64, false><<<(NU + 127) / 128, 256, 0, stream>>>(U, Wp_d1, u1, NU);
  k_gemm<64, 64, false><<<(NU + 127) / 128, 256, 0, stream>>>(U, Wp_d2, u2, NU);
  k_score<<<gE, 256, 0, stream>>>(u1, I1, src_d1, dst_d1, out, E);
  k_score<<<gE, 256, 0, stream>>>(u2, I2, src_d2, dst_d2, out + E, E);
}

// Round 6
// 4235.431 us; speedup vs baseline: 1.0854x; 1.0854x over previous
//
#include <hip/hip_runtime.h>
#include <hip/hip_bf16.h>

typedef unsigned short ushort_t;

// ---------------- problem constants ----------------
constexpr int NU = 100000, N1 = 60000, N2 = 60000;
constexpr int E = 2000000;
constexpr int TOTN = 2 * NU + N1 + N2;  // deg/norm layout: [du1|di1|du2|di2]
constexpr int NPART = 8;                // XCD partitions (blockIdx % 8 ~ XCD)
constexpr int NCHUNK = 256;             // edge chunks; grid = NPART*NCHUNK
constexpr int CHUNK_E = (E + NCHUNK - 1) / NCHUNK;
constexpr int PSLICE = TOTN / NPART;    // 40000 exactly

__device__ __forceinline__ ushort_t f2bf(float f) {
  unsigned u = __float_as_uint(f);
  u = u + 0x7fffu + ((u >> 16) & 1u);   // round-to-nearest-even
  return (ushort_t)(u >> 16);
}

// ---------------- degree count (XCD-partitioned) ----------------
__global__ __launch_bounds__(256) void k_count(const int* __restrict__ s1,
                                               const int* __restrict__ d1,
                                               const int* __restrict__ s2,
                                               const int* __restrict__ d2,
                                               int* __restrict__ deg) {
  int part = blockIdx.x & (NPART - 1);
  int chunk = blockIdx.x / NPART;
  int lo = part * PSLICE, hi = lo + PSLICE;
  int e1 = CHUNK_E * chunk + CHUNK_E < E ? CHUNK_E * chunk + CHUNK_E : E;
  for (int e = CHUNK_E * chunk + threadIdx.x; e < e1; e += 256) {
    int i0 = s1[e];
    int i1 = NU + d1[e];
    int i2 = NU + N1 + s2[e];
    int i3 = 2 * NU + N1 + d2[e];
    if (i0 >= lo && i0 < hi) atomicAdd(&deg[i0], 1);
    if (i1 >= lo && i1 < hi) atomicAdd(&deg[i1], 1);
    if (i2 >= lo && i2 < hi) atomicAdd(&deg[i2], 1);
    if (i3 >= lo && i3 < hi) atomicAdd(&deg[i3], 1);
  }
}

// ---------------- normalizers ----------------
__global__ __launch_bounds__(256) void k_norm(const int* __restrict__ deg,
                                              float* __restrict__ nrm) {
  int i = blockIdx.x * 256 + threadIdx.x;
  if (i >= TOTN) return;
  int d = deg[i];
  nrm[i] = rsqrtf((float)(d > 1 ? d : 1));
}

// ---------------- batched exclusive prefix scan (4 segments) ----------------
__global__ __launch_bounds__(256) void k_scan(const int* __restrict__ deg,
                                              int* __restrict__ off,
                                              int* __restrict__ cur) {
  __shared__ int wsum[4];
  int seg = blockIdx.x;
  int baseIn, n, baseOut;
  if (seg == 0)      { baseIn = 0;            n = NU; baseOut = 0; }
  else if (seg == 1) { baseIn = NU;           n = N1; baseOut = NU + 1; }
  else if (seg == 2) { baseIn = NU + N1;      n = NU; baseOut = NU + N1 + 2; }
  else               { baseIn = 2 * NU + N1;  n = N2; baseOut = 2 * NU + N1 + 3; }
  const int* in = deg + baseIn;
  int* out = off + baseOut;
  int* curp = cur + baseIn;

  constexpr int ITEMS = 16;            // 256*16 = 4096 per chunk
  int t = threadIdx.x, lane = t & 63, wid = t >> 6;
  int carry = 0;
  for (int base = 0; base < n; base += 256 * ITEMS) {
    int vals[ITEMS];
    int lsum = 0;
    int i0 = base + t * ITEMS;
#pragma unroll
    for (int j = 0; j < ITEMS; ++j) {
      int i = i0 + j;
      int v = (i < n) ? in[i] : 0;
      vals[j] = v;
      lsum += v;
    }
    int incl = lsum;
#pragma unroll
    for (int d = 1; d < 64; d <<= 1) {
      int x = __shfl_up(incl, d, 64);
      if (lane >= d) incl += x;
    }
    if (lane == 63) wsum[wid] = incl;
    __syncthreads();
    int woff = 0;
    for (int w = 0; w < wid; ++w) woff += wsum[w];
    int chunkTotal = wsum[0] + wsum[1] + wsum[2] + wsum[3];
    int excl = carry + woff + (incl - lsum);
#pragma unroll
    for (int j = 0; j < ITEMS; ++j) {
      int i = i0 + j;
      if (i < n) { out[i] = excl; curp[i] = excl; }
      excl += vals[j];
    }
    carry += chunkTotal;
    __syncthreads();
  }
  if (t == 0) out[n] = carry;
}

// ---------------- adjacency fill (XCD-partitioned) ----------------
__global__ __launch_bounds__(256) void k_fill(const int* __restrict__ s1,
                                              const int* __restrict__ d1,
                                              const int* __restrict__ s2,
                                              const int* __restrict__ d2,
                                              int* __restrict__ cur,
                                              int* __restrict__ a_s1,
                                              int* __restrict__ a_d1,
                                              int* __restrict__ a_s2,
                                              int* __restrict__ a_d2) {
  int part = blockIdx.x & (NPART - 1);
  int chunk = blockIdx.x / NPART;
  int lo = part * PSLICE, hi = lo + PSLICE;
  int e1 = CHUNK_E * chunk + CHUNK_E < E ? CHUNK_E * chunk + CHUNK_E : E;
  for (int e = CHUNK_E * chunk + threadIdx.x; e < e1; e += 256) {
    int a = s1[e], b = d1[e];
    int i0 = a, i1 = NU + b;
    if (i0 >= lo && i0 < hi) a_s1[atomicAdd(&cur[i0], 1)] = b;
    if (i1 >= lo && i1 < hi) a_d1[atomicAdd(&cur[i1], 1)] = a;
    int c = s2[e], d = d2[e];
    int i2 = NU + N1 + c, i3 = 2 * NU + N1 + d;
    if (i2 >= lo && i2 < hi) a_s2[atomicAdd(&cur[i2], 1)] = d;
    if (i3 >= lo && i3 < hi) a_d2[atomicAdd(&cur[i3], 1)] = c;
  }
}

// ---------------- dense GEMM: C[M][N] = rowscale ⊙ (A[M][K] @ W[K][N]) ----------------
// BF16OUT: C is bf16 (ushort), else fp32. 32KB max LDS (two-stage K).
template <int K, int N, bool BF16OUT>
__global__ __launch_bounds__(256) void k_gemm(const float* __restrict__ A,
                                              const float* __restrict__ W,
                                              void* __restrict__ Cv, int M,
                                              const float* __restrict__ rowscale) {
  constexpr int CG = N / 8;        // colgroups
  constexpr int RG = 256 / CG;     // rowgroups
  constexpr int RPB = RG * 4;      // rows per block
  __shared__ float sW[64 * N];
  int cg = threadIdx.x % CG, rg = threadIdx.x / CG;
  int r0 = blockIdx.x * RPB + rg * 4;
  int c0 = cg * 8;
  float acc[4][8] = {};
  for (int k0 = 0; k0 < K; k0 += 64) {
    if (k0) __syncthreads();
    for (int i = threadIdx.x * 4; i < 64 * N; i += 256 * 4)
      *(float4*)&sW[i] = *(const float4*)&W[k0 * N + i];
    __syncthreads();
    for (int k = 0; k < 64; k += 4) {
      float4 a[4];
#pragma unroll
      for (int r = 0; r < 4; ++r) {
        int rr = r0 + r; if (rr > M - 1) rr = M - 1;
        a[r] = *(const float4*)&A[(size_t)rr * K + k0 + k];
      }
#pragma unroll
      for (int kk = 0; kk < 4; ++kk) {
        float w[8];
        *(float4*)&w[0] = *(const float4*)&sW[(k + kk) * N + c0];
        *(float4*)&w[4] = *(const float4*)&sW[(k + kk) * N + c0 + 4];
#pragma unroll
        for (int r = 0; r < 4; ++r) {
          float av = kk == 0 ? a[r].x : kk == 1 ? a[r].y : kk == 2 ? a[r].z : a[r].w;
#pragma unroll
          for (int j = 0; j < 8; ++j) acc[r][j] += av * w[j];
        }
      }
    }
  }
#pragma unroll
  for (int r = 0; r < 4; ++r) {
    int rr = r0 + r;
    if (rr >= M) break;
    float sc = rowscale ? rowscale[rr] : 1.f;
    if constexpr (BF16OUT) {
      ushort_t* C = (ushort_t*)Cv;
      union { ushort_t h[8]; int4 v; } u_;
#pragma unroll
      for (int j = 0; j < 8; ++j) u_.h[j] = f2bf(sc * acc[r][j]);
      *(int4*)&C[(size_t)rr * N + c0] = u_.v;
    } else {
      float* C = (float*)Cv;
#pragma unroll
      for (int j = 0; j < 8; j += 4) {
        float4 v4;
        v4.x = sc * acc[r][j]; v4.y = sc * acc[r][j + 1];
        v4.z = sc * acc[r][j + 2]; v4.w = sc * acc[r][j + 3];
        *(float4*)&C[(size_t)rr * N + c0 + j] = v4;
      }
    }
  }
}

// ---------------- CSR gather from bf16 z (src norm pre-folded into z) ----------------
// out[v*D + c] (=old+) ndst[v] * sum_{s in adj[off[v]..]} z[s*D+c] (+bias)
template <int D, bool ACCUM, bool RELU>
__global__ __launch_bounds__(256) void k_gather(const ushort_t* __restrict__ z,
                                                const int* __restrict__ off,
                                                const int* __restrict__ adj,
                                                const float* __restrict__ ndst,
                                                const float* __restrict__ bias,
                                                const float* __restrict__ bias2,
                                                float* __restrict__ out, int nv) {
  constexpr int LPN = D / 2;        // lanes per node (each lane: 2 channels)
  constexpr int NPB = 256 / LPN;    // nodes per block
  int t = threadIdx.x;
  int slot = t / LPN, l = t % LPN;
  int v = blockIdx.x * NPB + slot;
  if (v >= nv) return;
  int e0 = off[v], e1 = off[v + 1];
  float a0 = 0.f, a1 = 0.f;
  for (int e = e0; e < e1; ++e) {
    int s = adj[e];
    unsigned pk = *(const unsigned*)&z[(size_t)s * D + 2 * l];
    a0 += __uint_as_float(pk << 16);
    a1 += __uint_as_float(pk & 0xffff0000u);
  }
  float nd = ndst[v];
  float r0, r1;
  size_t o = (size_t)v * D + 2 * l;
  if constexpr (ACCUM) {
    float2 old = *(const float2*)&out[o];
    r0 = old.x + nd * a0;
    r1 = old.y + nd * a1;
  } else {
    float b0 = bias[2 * l], b1 = bias[2 * l + 1];
    if (bias2) { b0 += bias2[2 * l]; b1 += bias2[2 * l + 1]; }
    r0 = nd * a0 + b0;
    r1 = nd * a1 + b1;
  }
  if constexpr (RELU) { r0 = fmaxf(r0, 0.f); r1 = fmaxf(r1, 0.f); }
  float2 res; res.x = r0; res.y = r1;
  *(float2*)&out[o] = res;
}

// ---------------- edge scoring: out[e] = dot(u[src[e]], it[dst[e]]) over 64 ----------------
__global__ __launch_bounds__(256) void k_score(const float* __restrict__ u,
                                               const float* __restrict__ it,
                                               const int* __restrict__ src,
                                               const int* __restrict__ dst,
                                               float* __restrict__ out, int ne) {
  int e = blockIdx.x * 256 + threadIdx.x;
  if (e >= ne) return;
  const float4* a = (const float4*)(u + (size_t)src[e] * 64);
  const float4* b = (const float4*)(it + (size_t)dst[e] * 64);
  float s = 0.f;
#pragma unroll
  for (int j = 0; j < 16; ++j) {
    float4 x = a[j], y = b[j];
    s += x.x * y.x + x.y * y.y + x.z * y.z + x.w * y.w;
  }
  out[e] = s;
}

// ---------------- host launch ----------------
extern "C" void kernel_launch(void* const* d_in, const int* in_sizes, int n_in,
                              void* d_out, int out_size, void* d_ws, size_t ws_size,
                              hipStream_t stream) {
  const float* emb_user = (const float*)d_in[0];
  const float* emb_d1   = (const float*)d_in[1];
  const float* emb_d2   = (const float*)d_in[2];
  const float* W_in     = (const float*)d_in[3];
  const float* b_in     = (const float*)d_in[4];
  const float* W_hid    = (const float*)d_in[5];
  const float* b_hid    = (const float*)d_in[6];
  const float* W_out    = (const float*)d_in[7];
  const float* b_out    = (const float*)d_in[8];
  const float* Wp_d1    = (const float*)d_in[9];
  const float* Wp_d2    = (const float*)d_in[10];
  const int* src_d1     = (const int*)d_in[11];
  const int* dst_d1     = (const int*)d_in[12];
  const int* src_d2     = (const int*)d_in[13];
  const int* dst_d2     = (const int*)d_in[14];
  float* out = (float*)d_out;

  char* p = (char*)d_ws;
  auto alloc = [&](size_t bytes) {
    void* r = (void*)p;
    p += (bytes + 15) & ~(size_t)15;
    return r;
  };
  float* bufU[2] = {(float*)alloc((size_t)NU * 128 * 4), (float*)alloc((size_t)NU * 128 * 4)};
  float* bufI1 = (float*)alloc((size_t)N1 * 128 * 4);
  float* bufI2 = (float*)alloc((size_t)N2 * 128 * 4);
  ushort_t* m = (ushort_t*)alloc((size_t)NU * 128 * 2);  // bf16 GEMM staging
  float* nrm = (float*)alloc((size_t)TOTN * 4);
  int* deg = (int*)alloc((size_t)TOTN * 4);
  int* off = (int*)alloc((size_t)(TOTN + 4) * 4);
  int* cur = (int*)alloc((size_t)TOTN * 4);
  int* adj_s1 = (int*)alloc((size_t)E * 4);
  int* adj_d1 = (int*)alloc((size_t)E * 4);
  int* adj_s2 = (int*)alloc((size_t)E * 4);
  int* adj_d2 = (int*)alloc((size_t)E * 4);

  // ws guard: fail soft (absmax) instead of GPU fault if scratch too small
  if ((size_t)(p - (char*)d_ws) > ws_size) return;

  const float* nu1 = nrm;
  const float* ni1 = nrm + NU;
  const float* nu2 = nrm + NU + N1;
  const float* ni2 = nrm + 2 * NU + N1;
  const int* off_u1 = off;
  const int* off_i1 = off + NU + 1;
  const int* off_u2 = off + NU + N1 + 2;
  const int* off_i2 = off + 2 * NU + N1 + 3;

  int gE = (E + 255) / 256;

  // ---- graph preprocessing ----
  hipMemsetAsync(deg, 0, (size_t)TOTN * 4, stream);
  k_count<<<NPART * NCHUNK, 256, 0, stream>>>(src_d1, dst_d1, src_d2, dst_d2, deg);
  k_norm<<<(TOTN + 255) / 256, 256, 0, stream>>>(deg, nrm);
  k_scan<<<4, 256, 0, stream>>>(deg, off, cur);
  k_fill<<<NPART * NCHUNK, 256, 0, stream>>>(src_d1, dst_d1, src_d2, dst_d2, cur,
                                             adj_s1, adj_d1, adj_s2, adj_d2);

  // ---- 3 GraphConv layers ----
  // Per layer: u-side gathers first (old I1/I2 die after their GEMMs), then
  // i-sides from old U written in-place; U ping-pongs.
  const float* U = emb_user;
  const float* I1 = emb_d1;
  const float* I2 = emb_d2;
  for (int L = 0; L < 3; ++L) {
    const float* W = L == 0 ? W_in : L == 1 ? W_hid : W_out;
    const float* B = L == 0 ? b_in : L == 1 ? b_hid : b_out;
    float* uNew = bufU[L % 2];
    if (L < 2) {
      constexpr int Nc = 128;
      k_gemm<128, Nc, true><<<(N1 + 63) / 64, 256, 0, stream>>>(I1, W + 1 * 128 * Nc, m, N1, ni1);
      k_gather<Nc, false, false><<<(NU + 3) / 4, 256, 0, stream>>>(
          m, off_u1, adj_s1, nu1, B + 1 * Nc, B + 3 * Nc, uNew, NU);
      k_gemm<128, Nc, true><<<(N2 + 63) / 64, 256, 0, stream>>>(I2, W + 3 * 128 * Nc, m, N2, ni2);
      k_gather<Nc, true, true><<<(NU + 3) / 4, 256, 0, stream>>>(
          m, off_u2, adj_s2, nu2, nullptr, nullptr, uNew, NU);
      k_gemm<128, Nc, true><<<(NU + 63) / 64, 256, 0, stream>>>(U, W + 0 * 128 * Nc, m, NU, nu1);
      k_gather<Nc, false, true><<<(N1 + 3) / 4, 256, 0, stream>>>(
          m, off_i1, adj_d1, ni1, B + 0 * Nc, nullptr, bufI1, N1);
      k_gemm<128, Nc, true><<<(NU + 63) / 64, 256, 0, stream>>>(U, W + 2 * 128 * Nc, m, NU, nu2);
      k_gather<Nc, false, true><<<(N2 + 3) / 4, 256, 0, stream>>>(
          m, off_i2, adj_d2, ni2, B + 2 * Nc, nullptr, bufI2, N2);
    } else {
      constexpr int Nc = 64;
      k_gemm<128, Nc, true><<<(N1 + 127) / 128, 256, 0, stream>>>(I1, W + 1 * 128 * Nc, m, N1, ni1);
      k_gather<Nc, false, false><<<(NU + 7) / 8, 256, 0, stream>>>(
          m, off_u1, adj_s1, nu1, B + 1 * Nc, B + 3 * Nc, uNew, NU);
      k_gemm<128, Nc, true><<<(N2 + 127) / 128, 256, 0, stream>>>(I2, W + 3 * 128 * Nc, m, N2, ni2);
      k_gather<Nc, true, false><<<(NU + 7) / 8, 256, 0, stream>>>(
          m, off_u2, adj_s2, nu2, nullptr, nullptr, uNew, NU);
      k_gemm<128, Nc, true><<<(NU + 63) / 64, 256, 0, stream>>>(U, W + 0 * 128 * Nc, m, NU, nu1);
      k_gather<Nc, false, false><<<(N1 + 7) / 8, 256, 0, stream>>>(
          m, off_i1, adj_d1, ni1, B + 0 * Nc, nullptr, bufI1, N1);
      k_gemm<128, Nc, true><<<(NU + 63) / 64, 256, 0, stream>>>(U, W + 2 * 128 * Nc, m, NU, nu2);
      k_gather<Nc, false, false><<<(N2 + 7) / 8, 256, 0, stream>>>(
          m, off_i2, adj_d2, ni2, B + 2 * Nc, nullptr, bufI2, N2);
    }
    U = uNew;
    I1 = bufI1;
    I2 = bufI2;
  }

  // ---- projections + scoring ----
  float* u1 = bufU[1];
  float* u2 = bufU[1] + (size_t)NU * 64;
  k_gemm<64, 64, false><<<(NU + 127) / 128, 256, 0, stream>>>(U, Wp_d1, u1, NU, nullptr);
  k_gemm<64, 64, false><<<(NU + 127) / 128, 256, 0, stream>>>(U, Wp_d2, u2, NU, nullptr);
  k_score<<<gE, 256, 0, stream>>>(u1, I1, src_d1, dst_d1, out, E);
  k_score<<<gE, 256, 0, stream>>>(u2, I2, src_d2, dst_d2, out + E, E);
}

// Round 8
// 2891.818 us; speedup vs baseline: 1.5897x; 1.4646x over previous
//
#include <hip/hip_runtime.h>
#include <hip/hip_bf16.h>

typedef unsigned short ushort_t;
typedef __attribute__((ext_vector_type(8))) short bf16x8;
typedef __attribute__((ext_vector_type(4))) float f32x4;

// ---------------- problem constants ----------------
constexpr int NU = 100000, N1 = 60000, N2 = 60000;
constexpr int E = 2000000;
constexpr int TOTN = 2 * NU + N1 + N2;  // deg/norm layout: [du1|di1|du2|di2] = 320000
constexpr int NPART = 8;                // XCD partitions (blockIdx % 8 ~ XCD)
constexpr int CH = 2048;                // edges per LDS-staged chunk
constexpr int NCHUNKS = (E + CH - 1) / CH;   // 977
constexpr int PSLICE = TOTN / NPART;    // 40000
constexpr int NSUB = 8;                 // subslices per partition (L2 write-set 500KB)
constexpr int SUBS = PSLICE / NSUB;     // 5000

__device__ __forceinline__ ushort_t f2bf(float f) {
  unsigned u = __float_as_uint(f);
  u = u + 0x7fffu + ((u >> 16) & 1u);   // round-to-nearest-even
  return (ushort_t)(u >> 16);
}

// ---------------- degree count (LDS chunk + XCD-partitioned subslices) ----------------
__global__ __launch_bounds__(256) void k_count(const int* __restrict__ s1,
                                               const int* __restrict__ d1,
                                               const int* __restrict__ s2,
                                               const int* __restrict__ d2,
                                               int* __restrict__ deg) {
  __shared__ int ls1[CH], ld1[CH], ls2[CH], ld2[CH];
  int part = blockIdx.x % NPART;
  int base = (blockIdx.x / NPART) * CH;
  int n = E - base; if (n > CH) n = CH;
  for (int i = threadIdx.x; i < n; i += 256) {
    ls1[i] = s1[base + i];
    ld1[i] = d1[base + i];
    ls2[i] = s2[base + i];
    ld2[i] = d2[base + i];
  }
  __syncthreads();
  int plo = part * PSLICE;
  for (int sub = 0; sub < NSUB; ++sub) {
    int lo = plo + sub * SUBS, hi = lo + SUBS;
    for (int i = threadIdx.x; i < n; i += 256) {
      int i0 = ls1[i];
      int i1 = NU + ld1[i];
      int i2 = NU + N1 + ls2[i];
      int i3 = 2 * NU + N1 + ld2[i];
      if (i0 >= lo && i0 < hi) atomicAdd(&deg[i0], 1);
      if (i1 >= lo && i1 < hi) atomicAdd(&deg[i1], 1);
      if (i2 >= lo && i2 < hi) atomicAdd(&deg[i2], 1);
      if (i3 >= lo && i3 < hi) atomicAdd(&deg[i3], 1);
    }
    __syncthreads();
  }
}

// ---------------- normalizers ----------------
__global__ __launch_bounds__(256) void k_norm(const int* __restrict__ deg,
                                              float* __restrict__ nrm) {
  int i = blockIdx.x * 256 + threadIdx.x;
  if (i >= TOTN) return;
  int d = deg[i];
  nrm[i] = rsqrtf((float)(d > 1 ? d : 1));
}

// ---------------- batched exclusive prefix scan (4 segments) ----------------
__global__ __launch_bounds__(256) void k_scan(const int* __restrict__ deg,
                                              int* __restrict__ off,
                                              int* __restrict__ cur) {
  __shared__ int wsum[4];
  int seg = blockIdx.x;
  int baseIn, n, baseOut;
  if (seg == 0)      { baseIn = 0;            n = NU; baseOut = 0; }
  else if (seg == 1) { baseIn = NU;           n = N1; baseOut = NU + 1; }
  else if (seg == 2) { baseIn = NU + N1;      n = NU; baseOut = NU + N1 + 2; }
  else               { baseIn = 2 * NU + N1;  n = N2; baseOut = 2 * NU + N1 + 3; }
  const int* in = deg + baseIn;
  int* out = off + baseOut;
  int* curp = cur + baseIn;

  constexpr int ITEMS = 16;
  int t = threadIdx.x, lane = t & 63, wid = t >> 6;
  int carry = 0;
  for (int base = 0; base < n; base += 256 * ITEMS) {
    int vals[ITEMS];
    int lsum = 0;
    int i0 = base + t * ITEMS;
#pragma unroll
    for (int j = 0; j < ITEMS; ++j) {
      int i = i0 + j;
      int v = (i < n) ? in[i] : 0;
      vals[j] = v;
      lsum += v;
    }
    int incl = lsum;
#pragma unroll
    for (int d = 1; d < 64; d <<= 1) {
      int x = __shfl_up(incl, d, 64);
      if (lane >= d) incl += x;
    }
    if (lane == 63) wsum[wid] = incl;
    __syncthreads();
    int woff = 0;
    for (int w = 0; w < wid; ++w) woff += wsum[w];
    int chunkTotal = wsum[0] + wsum[1] + wsum[2] + wsum[3];
    int excl = carry + woff + (incl - lsum);
#pragma unroll
    for (int j = 0; j < ITEMS; ++j) {
      int i = i0 + j;
      if (i < n) { out[i] = excl; curp[i] = excl; }
      excl += vals[j];
    }
    carry += chunkTotal;
    __syncthreads();
  }
  if (t == 0) out[n] = carry;
}

// ---------------- adjacency fill (LDS chunk + XCD-partitioned subslices) ----------------
__global__ __launch_bounds__(256) void k_fill(const int* __restrict__ s1,
                                              const int* __restrict__ d1,
                                              const int* __restrict__ s2,
                                              const int* __restrict__ d2,
                                              int* __restrict__ cur,
                                              int* __restrict__ a_s1,
                                              int* __restrict__ a_d1,
                                              int* __restrict__ a_s2,
                                              int* __restrict__ a_d2) {
  __shared__ int ls1[CH], ld1[CH], ls2[CH], ld2[CH];
  int part = blockIdx.x % NPART;
  int base = (blockIdx.x / NPART) * CH;
  int n = E - base; if (n > CH) n = CH;
  for (int i = threadIdx.x; i < n; i += 256) {
    ls1[i] = s1[base + i];
    ld1[i] = d1[base + i];
    ls2[i] = s2[base + i];
    ld2[i] = d2[base + i];
  }
  __syncthreads();
  int plo = part * PSLICE;
  for (int sub = 0; sub < NSUB; ++sub) {
    int lo = plo + sub * SUBS, hi = lo + SUBS;
    for (int i = threadIdx.x; i < n; i += 256) {
      int a = ls1[i], b = ld1[i];
      int i0 = a, i1 = NU + b;
      if (i0 >= lo && i0 < hi) a_s1[atomicAdd(&cur[i0], 1)] = b;
      if (i1 >= lo && i1 < hi) a_d1[atomicAdd(&cur[i1], 1)] = a;
      int c = ls2[i], d = ld2[i];
      int i2 = NU + N1 + c, i3 = 2 * NU + N1 + d;
      if (i2 >= lo && i2 < hi) a_s2[atomicAdd(&cur[i2], 1)] = d;
      if (i3 >= lo && i3 < hi) a_d2[atomicAdd(&cur[i3], 1)] = c;
    }
    __syncthreads();
  }
}

// ---------------- MFMA bf16 GEMM: C[M][N] = rowscale ⊙ (A[M][K] @ W[K][N]) ----------------
// A fp32 (cast to bf16 on load), W fp32 (staged to LDS as bf16, transposed [N][K],
// XOR-swizzled for conflict-free ds_read_b128). 4 waves, M-tile 64 (16 rows/wave).
// mfma_f32_16x16x32_bf16: A frag row=lane&15, k=(lane>>4)*8+i; B frag col=lane&15,
// same k; D frag col=lane&15, row=(lane>>4)*4+reg [m89-verified].
template <int K, int N, bool BF16OUT>
__global__ __launch_bounds__(256) void k_gemm(const float* __restrict__ A,
                                              const float* __restrict__ W,
                                              void* __restrict__ Cv, int M,
                                              const float* __restrict__ rowscale) {
  constexpr int KF = K / 32, NF = N / 16;
  __shared__ __align__(16) ushort_t sW[N * K];
  // stage W^T as bf16, swizzled: elem idx (n*K+k) ^ ((n&7)<<3)  [byte ^ ((n&7)<<4)]
  for (int i = threadIdx.x * 4; i < K * N; i += 1024) {
    float4 w4 = *(const float4*)&W[i];
    int k = i / N, n0 = i % N;
    float wv[4] = {w4.x, w4.y, w4.z, w4.w};
#pragma unroll
    for (int j = 0; j < 4; ++j) {
      int n = n0 + j;
      sW[(n * K + k) ^ ((n & 7) << 3)] = f2bf(wv[j]);
    }
  }
  __syncthreads();

  int w = threadIdx.x >> 6, lane = threadIdx.x & 63;
  int col = lane & 15, kg = lane >> 4;
  int r = blockIdx.x * 64 + w * 16 + col;
  int rA = r < M ? r : M - 1;

  bf16x8 af[KF];
#pragma unroll
  for (int kf = 0; kf < KF; ++kf) {
    const float* ap = &A[(size_t)rA * K + kf * 32 + kg * 8];
    float4 lo = *(const float4*)ap;
    float4 hi = *(const float4*)(ap + 4);
    bf16x8 v;
    v[0] = (short)f2bf(lo.x); v[1] = (short)f2bf(lo.y);
    v[2] = (short)f2bf(lo.z); v[3] = (short)f2bf(lo.w);
    v[4] = (short)f2bf(hi.x); v[5] = (short)f2bf(hi.y);
    v[6] = (short)f2bf(hi.z); v[7] = (short)f2bf(hi.w);
    af[kf] = v;
  }

  f32x4 acc[NF] = {};
#pragma unroll
  for (int nf = 0; nf < NF; ++nf) {
    int n = nf * 16 + col;
#pragma unroll
    for (int kf = 0; kf < KF; ++kf) {
      int idx = (n * K + kf * 32 + kg * 8) ^ ((n & 7) << 3);
      bf16x8 bfrag = *(const bf16x8*)&sW[idx];
      acc[nf] = __builtin_amdgcn_mfma_f32_16x16x32_bf16(af[kf], bfrag, acc[nf], 0, 0, 0);
    }
  }

  int orow = blockIdx.x * 64 + w * 16 + kg * 4;
#pragma unroll
  for (int reg = 0; reg < 4; ++reg) {
    int R = orow + reg;
    if (R >= M) break;
    float sc = rowscale ? rowscale[R] : 1.f;
#pragma unroll
    for (int nf = 0; nf < NF; ++nf) {
      float v = sc * acc[nf][reg];
      size_t o = (size_t)R * N + nf * 16 + col;
      if constexpr (BF16OUT) ((ushort_t*)Cv)[o] = f2bf(v);
      else                   ((float*)Cv)[o] = v;
    }
  }
}

// ---------------- CSR gather from bf16 z (src norm pre-folded into z) ----------------
// out[v*D + c] (=old+) ndst[v] * sum_{s in adj[off[v]..]} z[s*D+c] (+bias)
// 4 channels/lane (uint2 = 8B loads), 4-edge unroll for 4 rows in flight.
template <int D, bool ACCUM, bool RELU>
__global__ __launch_bounds__(256) void k_gather(const ushort_t* __restrict__ z,
                                                const int* __restrict__ off,
                                                const int* __restrict__ adj,
                                                const float* __restrict__ ndst,
                                                const float* __restrict__ bias,
                                                const float* __restrict__ bias2,
                                                float* __restrict__ out, int nv) {
  constexpr int LPN = D / 4;        // lanes per node, 4 channels each
  constexpr int NPB = 256 / LPN;
  int t = threadIdx.x;
  int slot = t / LPN, l = t % LPN;
  int v = blockIdx.x * NPB + slot;
  if (v >= nv) return;
  int e0 = off[v], e1 = off[v + 1];
  float a0 = 0.f, a1 = 0.f, a2 = 0.f, a3 = 0.f;
  auto addp = [&](uint2 p) {
    a0 += __uint_as_float(p.x << 16);
    a1 += __uint_as_float(p.x & 0xffff0000u);
    a2 += __uint_as_float(p.y << 16);
    a3 += __uint_as_float(p.y & 0xffff0000u);
  };
  int e = e0;
  for (; e + 4 <= e1; e += 4) {
    int sA = adj[e], sB = adj[e + 1], sC = adj[e + 2], sD = adj[e + 3];
    uint2 pA = *(const uint2*)&z[(size_t)sA * D + 4 * l];
    uint2 pB = *(const uint2*)&z[(size_t)sB * D + 4 * l];
    uint2 pC = *(const uint2*)&z[(size_t)sC * D + 4 * l];
    uint2 pD = *(const uint2*)&z[(size_t)sD * D + 4 * l];
    addp(pA); addp(pB); addp(pC); addp(pD);
  }
  for (; e < e1; ++e) {
    int s = adj[e];
    addp(*(const uint2*)&z[(size_t)s * D + 4 * l]);
  }
  float nd = ndst[v];
  size_t o = (size_t)v * D + 4 * l;
  float r0, r1, r2, r3;
  if constexpr (ACCUM) {
    float4 old = *(const float4*)&out[o];
    r0 = old.x + nd * a0; r1 = old.y + nd * a1;
    r2 = old.z + nd * a2; r3 = old.w + nd * a3;
  } else {
    float b0 = bias[4 * l], b1 = bias[4 * l + 1], b2 = bias[4 * l + 2], b3 = bias[4 * l + 3];
    if (bias2) {
      b0 += bias2[4 * l]; b1 += bias2[4 * l + 1];
      b2 += bias2[4 * l + 2]; b3 += bias2[4 * l + 3];
    }
    r0 = nd * a0 + b0; r1 = nd * a1 + b1; r2 = nd * a2 + b2; r3 = nd * a3 + b3;
  }
  if constexpr (RELU) {
    r0 = fmaxf(r0, 0.f); r1 = fmaxf(r1, 0.f);
    r2 = fmaxf(r2, 0.f); r3 = fmaxf(r3, 0.f);
  }
  float4 res; res.x = r0; res.y = r1; res.z = r2; res.w = r3;
  *(float4*)&out[o] = res;
}

// ---------------- edge scoring: out[e] = dot(u[src[e]], it[dst[e]]) over 64 ----------------
__global__ __launch_bounds__(256) void k_score(const float* __restrict__ u,
                                               const float* __restrict__ it,
                                               const int* __restrict__ src,
                                               const int* __restrict__ dst,
                                               float* __restrict__ out, int ne) {
  int e = blockIdx.x * 256 + threadIdx.x;
  if (e >= ne) return;
  const float4* a = (const float4*)(u + (size_t)src[e] * 64);
  const float4* b = (const float4*)(it + (size_t)dst[e] * 64);
  float s = 0.f;
#pragma unroll
  for (int j = 0; j < 16; ++j) {
    float4 x = a[j], y = b[j];
    s += x.x * y.x + x.y * y.y + x.z * y.z + x.w * y.w;
  }
  out[e] = s;
}

// ---------------- host launch ----------------
extern "C" void kernel_launch(void* const* d_in, const int* in_sizes, int n_in,
                              void* d_out, int out_size, void* d_ws, size_t ws_size,
                              hipStream_t stream) {
  const float* emb_user = (const float*)d_in[0];
  const float* emb_d1   = (const float*)d_in[1];
  const float* emb_d2   = (const float*)d_in[2];
  const float* W_in     = (const float*)d_in[3];
  const float* b_in     = (const float*)d_in[4];
  const float* W_hid    = (const float*)d_in[5];
  const float* b_hid    = (const float*)d_in[6];
  const float* W_out    = (const float*)d_in[7];
  const float* b_out    = (const float*)d_in[8];
  const float* Wp_d1    = (const float*)d_in[9];
  const float* Wp_d2    = (const float*)d_in[10];
  const int* src_d1     = (const int*)d_in[11];
  const int* dst_d1     = (const int*)d_in[12];
  const int* src_d2     = (const int*)d_in[13];
  const int* dst_d2     = (const int*)d_in[14];
  float* out = (float*)d_out;

  char* p = (char*)d_ws;
  auto alloc = [&](size_t bytes) {
    void* r = (void*)p;
    p += (bytes + 15) & ~(size_t)15;
    return r;
  };
  float* bufU[2] = {(float*)alloc((size_t)NU * 128 * 4), (float*)alloc((size_t)NU * 128 * 4)};
  float* bufI1 = (float*)alloc((size_t)N1 * 128 * 4);
  float* bufI2 = (float*)alloc((size_t)N2 * 128 * 4);
  ushort_t* m = (ushort_t*)alloc((size_t)NU * 128 * 2);  // bf16 GEMM staging
  float* nrm = (float*)alloc((size_t)TOTN * 4);
  int* deg = (int*)alloc((size_t)TOTN * 4);
  int* off = (int*)alloc((size_t)(TOTN + 4) * 4);
  int* cur = (int*)alloc((size_t)TOTN * 4);
  int* adj_s1 = (int*)alloc((size_t)E * 4);
  int* adj_d1 = (int*)alloc((size_t)E * 4);
  int* adj_s2 = (int*)alloc((size_t)E * 4);
  int* adj_d2 = (int*)alloc((size_t)E * 4);

  // ws guard: fail soft (absmax) instead of GPU fault if scratch too small
  if ((size_t)(p - (char*)d_ws) > ws_size) return;

  const float* nu1 = nrm;
  const float* ni1 = nrm + NU;
  const float* nu2 = nrm + NU + N1;
  const float* ni2 = nrm + 2 * NU + N1;
  const int* off_u1 = off;
  const int* off_i1 = off + NU + 1;
  const int* off_u2 = off + NU + N1 + 2;
  const int* off_i2 = off + 2 * NU + N1 + 3;

  int gE = (E + 255) / 256;

  // ---- graph preprocessing ----
  hipMemsetAsync(deg, 0, (size_t)TOTN * 4, stream);
  k_count<<<NCHUNKS * NPART, 256, 0, stream>>>(src_d1, dst_d1, src_d2, dst_d2, deg);
  k_norm<<<(TOTN + 255) / 256, 256, 0, stream>>>(deg, nrm);
  k_scan<<<4, 256, 0, stream>>>(deg, off, cur);
  k_fill<<<NCHUNKS * NPART, 256, 0, stream>>>(src_d1, dst_d1, src_d2, dst_d2, cur,
                                              adj_s1, adj_d1, adj_s2, adj_d2);

  // ---- 3 GraphConv layers ----
  // Per layer: u-side gathers first (old I1/I2 die after their GEMMs), then
  // i-sides from old U written in-place; U ping-pongs.
  const float* U = emb_user;
  const float* I1 = emb_d1;
  const float* I2 = emb_d2;
  for (int L = 0; L < 3; ++L) {
    const float* W = L == 0 ? W_in : L == 1 ? W_hid : W_out;
    const float* B = L == 0 ? b_in : L == 1 ? b_hid : b_out;
    float* uNew = bufU[L % 2];
    if (L < 2) {
      constexpr int Nc = 128;
      k_gemm<128, Nc, true><<<(N1 + 63) / 64, 256, 0, stream>>>(I1, W + 1 * 128 * Nc, m, N1, ni1);
      k_gather<Nc, false, false><<<(NU + 7) / 8, 256, 0, stream>>>(
          m, off_u1, adj_s1, nu1, B + 1 * Nc, B + 3 * Nc, uNew, NU);
      k_gemm<128, Nc, true><<<(N2 + 63) / 64, 256, 0, stream>>>(I2, W + 3 * 128 * Nc, m, N2, ni2);
      k_gather<Nc, true, true><<<(NU + 7) / 8, 256, 0, stream>>>(
          m, off_u2, adj_s2, nu2, nullptr, nullptr, uNew, NU);
      k_gemm<128, Nc, true><<<(NU + 63) / 64, 256, 0, stream>>>(U, W + 0 * 128 * Nc, m, NU, nu1);
      k_gather<Nc, false, true><<<(N1 + 7) / 8, 256, 0, stream>>>(
          m, off_i1, adj_d1, ni1, B + 0 * Nc, nullptr, bufI1, N1);
      k_gemm<128, Nc, true><<<(NU + 63) / 64, 256, 0, stream>>>(U, W + 2 * 128 * Nc, m, NU, nu2);
      k_gather<Nc, false, true><<<(N2 + 7) / 8, 256, 0, stream>>>(
          m, off_i2, adj_d2, ni2, B + 2 * Nc, nullptr, bufI2, N2);
    } else {
      constexpr int Nc = 64;
      k_gemm<128, Nc, true><<<(N1 + 63) / 64, 256, 0, stream>>>(I1, W + 1 * 128 * Nc, m, N1, ni1);
      k_gather<Nc, false, false><<<(NU + 15) / 16, 256, 0, stream>>>(
          m, off_u1, adj_s1, nu1, B + 1 * Nc, B + 3 * Nc, uNew, NU);
      k_gemm<128, Nc, true><<<(N2 + 63) / 64, 256, 0, stream>>>(I2, W + 3 * 128 * Nc, m, N2, ni2);
      k_gather<Nc, true, false><<<(NU + 15) / 16, 256, 0, stream>>>(
          m, off_u2, adj_s2, nu2, nullptr, nullptr, uNew, NU);
      k_gemm<128, Nc, true><<<(NU + 63) / 64, 256, 0, stream>>>(U, W + 0 * 128 * Nc, m, NU, nu1);
      k_gather<Nc, false, false><<<(N1 + 15) / 16, 256, 0, stream>>>(
          m, off_i1, adj_d1, ni1, B + 0 * Nc, nullptr, bufI1, N1);
      k_gemm<128, Nc, true><<<(NU + 63) / 64, 256, 0, stream>>>(U, W + 2 * 128 * Nc, m, NU, nu2);
      k_gather<Nc, false, false><<<(N2 + 15) / 16, 256, 0, stream>>>(
          m, off_i2, adj_d2, ni2, B + 2 * Nc, nullptr, bufI2, N2);
    }
    U = uNew;
    I1 = bufI1;
    I2 = bufI2;
  }

  // ---- projections + scoring ----
  float* u1 = bufU[1];
  float* u2 = bufU[1] + (size_t)NU * 64;
  k_gemm<64, 64, false><<<(NU + 63) / 64, 256, 0, stream>>>(U, Wp_d1, u1, NU, nullptr);
  k_gemm<64, 64, false><<<(NU + 63) / 64, 256, 0, stream>>>(U, Wp_d2, u2, NU, nullptr);
  k_score<<<gE, 256, 0, stream>>>(u1, I1, src_d1, dst_d1, out, E);
  k_score<<<gE, 256, 0, stream>>>(u2, I2, src_d2, dst_d2, out + E, E);
}

// Round 9
// 2385.529 us; speedup vs baseline: 1.9271x; 1.2122x over previous
//
#include <hip/hip_runtime.h>
#include <hip/hip_bf16.h>

typedef unsigned short ushort_t;
typedef __attribute__((ext_vector_type(8))) short bf16x8;
typedef __attribute__((ext_vector_type(4))) float f32x4;

// ---------------- problem constants ----------------
constexpr int NU = 100000, N1 = 60000, N2 = 60000;
constexpr int E = 2000000;
constexpr int TOTN = 2 * NU + N1 + N2;  // deg/norm layout: [du1|di1|du2|di2] = 320000
constexpr int NPART = 8;                // XCD partitions (blockIdx % 8 ~ XCD)
constexpr int CH = 2048;                // edges per LDS-staged chunk
constexpr int NCHUNKS = (E + CH - 1) / CH;
constexpr int PSLICE = TOTN / NPART;    // 40000
constexpr int NSUB = 8;                 // subslices per partition
constexpr int SUBS = PSLICE / NSUB;     // 5000

__device__ __forceinline__ ushort_t f2bf(float f) {
  unsigned u = __float_as_uint(f);
  u = u + 0x7fffu + ((u >> 16) & 1u);   // round-to-nearest-even
  return (ushort_t)(u >> 16);
}

// ---------------- degree count (LDS chunk + XCD-partitioned subslices) ----------------
__global__ __launch_bounds__(256) void k_count(const int* __restrict__ s1,
                                               const int* __restrict__ d1,
                                               const int* __restrict__ s2,
                                               const int* __restrict__ d2,
                                               int* __restrict__ deg) {
  __shared__ int ls1[CH], ld1[CH], ls2[CH], ld2[CH];
  int part = blockIdx.x % NPART;
  int base = (blockIdx.x / NPART) * CH;
  int n = E - base; if (n > CH) n = CH;
  for (int i = threadIdx.x; i < n; i += 256) {
    ls1[i] = s1[base + i];
    ld1[i] = d1[base + i];
    ls2[i] = s2[base + i];
    ld2[i] = d2[base + i];
  }
  __syncthreads();
  int plo = part * PSLICE;
  for (int sub = 0; sub < NSUB; ++sub) {
    int lo = plo + sub * SUBS, hi = lo + SUBS;
    for (int i = threadIdx.x; i < n; i += 256) {
      int i0 = ls1[i];
      int i1 = NU + ld1[i];
      int i2 = NU + N1 + ls2[i];
      int i3 = 2 * NU + N1 + ld2[i];
      if (i0 >= lo && i0 < hi) atomicAdd(&deg[i0], 1);
      if (i1 >= lo && i1 < hi) atomicAdd(&deg[i1], 1);
      if (i2 >= lo && i2 < hi) atomicAdd(&deg[i2], 1);
      if (i3 >= lo && i3 < hi) atomicAdd(&deg[i3], 1);
    }
    __syncthreads();
  }
}

// ---------------- normalizers ----------------
__global__ __launch_bounds__(256) void k_norm(const int* __restrict__ deg,
                                              float* __restrict__ nrm) {
  int i = blockIdx.x * 256 + threadIdx.x;
  if (i >= TOTN) return;
  int d = deg[i];
  nrm[i] = rsqrtf((float)(d > 1 ? d : 1));
}

// ---------------- batched exclusive prefix scan (4 segments) ----------------
__global__ __launch_bounds__(256) void k_scan(const int* __restrict__ deg,
                                              int* __restrict__ off,
                                              int* __restrict__ cur) {
  __shared__ int wsum[4];
  int seg = blockIdx.x;
  int baseIn, n, baseOut;
  if (seg == 0)      { baseIn = 0;            n = NU; baseOut = 0; }
  else if (seg == 1) { baseIn = NU;           n = N1; baseOut = NU + 1; }
  else if (seg == 2) { baseIn = NU + N1;      n = NU; baseOut = NU + N1 + 2; }
  else               { baseIn = 2 * NU + N1;  n = N2; baseOut = 2 * NU + N1 + 3; }
  const int* in = deg + baseIn;
  int* out = off + baseOut;
  int* curp = cur + baseIn;

  constexpr int ITEMS = 16;
  int t = threadIdx.x, lane = t & 63, wid = t >> 6;
  int carry = 0;
  for (int base = 0; base < n; base += 256 * ITEMS) {
    int vals[ITEMS];
    int lsum = 0;
    int i0 = base + t * ITEMS;
#pragma unroll
    for (int j = 0; j < ITEMS; ++j) {
      int i = i0 + j;
      int v = (i < n) ? in[i] : 0;
      vals[j] = v;
      lsum += v;
    }
    int incl = lsum;
#pragma unroll
    for (int d = 1; d < 64; d <<= 1) {
      int x = __shfl_up(incl, d, 64);
      if (lane >= d) incl += x;
    }
    if (lane == 63) wsum[wid] = incl;
    __syncthreads();
    int woff = 0;
    for (int w = 0; w < wid; ++w) woff += wsum[w];
    int chunkTotal = wsum[0] + wsum[1] + wsum[2] + wsum[3];
    int excl = carry + woff + (incl - lsum);
#pragma unroll
    for (int j = 0; j < ITEMS; ++j) {
      int i = i0 + j;
      if (i < n) { out[i] = excl; curp[i] = excl; }
      excl += vals[j];
    }
    carry += chunkTotal;
    __syncthreads();
  }
  if (t == 0) out[n] = carry;
}

// ---------------- adjacency fill (LDS chunk + subslices; eids for user lists) ----------------
__global__ __launch_bounds__(256) void k_fill(const int* __restrict__ s1,
                                              const int* __restrict__ d1,
                                              const int* __restrict__ s2,
                                              const int* __restrict__ d2,
                                              int* __restrict__ cur,
                                              int* __restrict__ a_s1,
                                              int* __restrict__ a_d1,
                                              int* __restrict__ a_s2,
                                              int* __restrict__ a_d2,
                                              int* __restrict__ e_s1,
                                              int* __restrict__ e_s2) {
  __shared__ int ls1[CH], ld1[CH], ls2[CH], ld2[CH];
  int part = blockIdx.x % NPART;
  int base = (blockIdx.x / NPART) * CH;
  int n = E - base; if (n > CH) n = CH;
  for (int i = threadIdx.x; i < n; i += 256) {
    ls1[i] = s1[base + i];
    ld1[i] = d1[base + i];
    ls2[i] = s2[base + i];
    ld2[i] = d2[base + i];
  }
  __syncthreads();
  int plo = part * PSLICE;
  for (int sub = 0; sub < NSUB; ++sub) {
    int lo = plo + sub * SUBS, hi = lo + SUBS;
    for (int i = threadIdx.x; i < n; i += 256) {
      int a = ls1[i], b = ld1[i];
      int i0 = a, i1 = NU + b;
      if (i0 >= lo && i0 < hi) {
        int pos = atomicAdd(&cur[i0], 1);
        a_s1[pos] = b;
        e_s1[pos] = base + i;
      }
      if (i1 >= lo && i1 < hi) a_d1[atomicAdd(&cur[i1], 1)] = a;
      int c = ls2[i], d = ld2[i];
      int i2 = NU + N1 + c, i3 = 2 * NU + N1 + d;
      if (i2 >= lo && i2 < hi) {
        int pos = atomicAdd(&cur[i2], 1);
        a_s2[pos] = d;
        e_s2[pos] = base + i;
      }
      if (i3 >= lo && i3 < hi) a_d2[atomicAdd(&cur[i3], 1)] = c;
    }
    __syncthreads();
  }
}

// ---------------- MFMA bf16 GEMM: C[M][N] = rowscale ⊙ (A[M][K] @ W[K][N]) ----------------
__device__ __forceinline__ bf16x8 loadA8(const float* p) {
  float4 lo = *(const float4*)p;
  float4 hi = *(const float4*)(p + 4);
  bf16x8 v;
  v[0] = (short)f2bf(lo.x); v[1] = (short)f2bf(lo.y);
  v[2] = (short)f2bf(lo.z); v[3] = (short)f2bf(lo.w);
  v[4] = (short)f2bf(hi.x); v[5] = (short)f2bf(hi.y);
  v[6] = (short)f2bf(hi.z); v[7] = (short)f2bf(hi.w);
  return v;
}
__device__ __forceinline__ bf16x8 loadA8(const ushort_t* p) {
  return *(const bf16x8*)p;
}

template <typename AT, int K, int N, bool BF16OUT>
__global__ __launch_bounds__(256) void k_gemm(const AT* __restrict__ A,
                                              const float* __restrict__ W,
                                              void* __restrict__ Cv, int M,
                                              const float* __restrict__ rowscale) {
  constexpr int KF = K / 32, NF = N / 16;
  __shared__ __align__(16) ushort_t sW[N * K];
  for (int i = threadIdx.x * 4; i < K * N; i += 1024) {
    float4 w4 = *(const float4*)&W[i];
    int k = i / N, n0 = i % N;
    float wv[4] = {w4.x, w4.y, w4.z, w4.w};
#pragma unroll
    for (int j = 0; j < 4; ++j) {
      int n = n0 + j;
      sW[(n * K + k) ^ ((n & 7) << 3)] = f2bf(wv[j]);
    }
  }
  __syncthreads();

  int w = threadIdx.x >> 6, lane = threadIdx.x & 63;
  int col = lane & 15, kg = lane >> 4;
  int r = blockIdx.x * 64 + w * 16 + col;
  int rA = r < M ? r : M - 1;

  bf16x8 af[KF];
#pragma unroll
  for (int kf = 0; kf < KF; ++kf)
    af[kf] = loadA8(&A[(size_t)rA * K + kf * 32 + kg * 8]);

  f32x4 acc[NF] = {};
#pragma unroll
  for (int nf = 0; nf < NF; ++nf) {
    int n = nf * 16 + col;
#pragma unroll
    for (int kf = 0; kf < KF; ++kf) {
      int idx = (n * K + kf * 32 + kg * 8) ^ ((n & 7) << 3);
      bf16x8 bfrag = *(const bf16x8*)&sW[idx];
      acc[nf] = __builtin_amdgcn_mfma_f32_16x16x32_bf16(af[kf], bfrag, acc[nf], 0, 0, 0);
    }
  }

  int orow = blockIdx.x * 64 + w * 16 + kg * 4;
#pragma unroll
  for (int reg = 0; reg < 4; ++reg) {
    int R = orow + reg;
    if (R >= M) break;
    float sc = rowscale ? rowscale[R] : 1.f;
#pragma unroll
    for (int nf = 0; nf < NF; ++nf) {
      float v = sc * acc[nf][reg];
      size_t o = (size_t)R * N + nf * 16 + col;
      if constexpr (BF16OUT) ((ushort_t*)Cv)[o] = f2bf(v);
      else                   ((float*)Cv)[o] = v;
    }
  }
}

// ---------------- CSR list accumulation helper (bf16 z, 4 ch/lane) ----------------
template <int D>
__device__ __forceinline__ void accum_list(const ushort_t* __restrict__ z,
                                           const int* __restrict__ adj,
                                           int e0, int e1, int l, float4& A) {
  auto addp = [&](uint2 p) {
    A.x += __uint_as_float(p.x << 16);
    A.y += __uint_as_float(p.x & 0xffff0000u);
    A.z += __uint_as_float(p.y << 16);
    A.w += __uint_as_float(p.y & 0xffff0000u);
  };
  int e = e0;
  for (; e + 4 <= e1; e += 4) {
    int sA = adj[e], sB = adj[e + 1], sC = adj[e + 2], sD = adj[e + 3];
    uint2 pA = *(const uint2*)&z[(size_t)sA * D + 4 * l];
    uint2 pB = *(const uint2*)&z[(size_t)sB * D + 4 * l];
    uint2 pC = *(const uint2*)&z[(size_t)sC * D + 4 * l];
    uint2 pD = *(const uint2*)&z[(size_t)sD * D + 4 * l];
    addp(pA); addp(pB); addp(pC); addp(pD);
  }
  for (; e < e1; ++e)
    addp(*(const uint2*)&z[(size_t)adj[e] * D + 4 * l]);
}

// ---------------- single-list CSR gather (item sides) ----------------
template <int D, bool RELU, bool BF16OUT>
__global__ __launch_bounds__(256) void k_gather(const ushort_t* __restrict__ z,
                                                const int* __restrict__ off,
                                                const int* __restrict__ adj,
                                                const float* __restrict__ ndst,
                                                const float* __restrict__ bias,
                                                void* __restrict__ outv, int nv) {
  constexpr int LPN = D / 4;
  constexpr int NPB = 256 / LPN;
  int t = threadIdx.x;
  int slot = t / LPN, l = t % LPN;
  int v = blockIdx.x * NPB + slot;
  if (v >= nv) return;
  float4 A = {0.f, 0.f, 0.f, 0.f};
  accum_list<D>(z, adj, off[v], off[v + 1], l, A);
  float nd = ndst[v];
  float r0 = nd * A.x + bias[4 * l];
  float r1 = nd * A.y + bias[4 * l + 1];
  float r2 = nd * A.z + bias[4 * l + 2];
  float r3 = nd * A.w + bias[4 * l + 3];
  if constexpr (RELU) {
    r0 = fmaxf(r0, 0.f); r1 = fmaxf(r1, 0.f);
    r2 = fmaxf(r2, 0.f); r3 = fmaxf(r3, 0.f);
  }
  size_t o = (size_t)v * D + 4 * l;
  if constexpr (BF16OUT) {
    uint2 pk;
    pk.x = (unsigned)f2bf(r0) | ((unsigned)f2bf(r1) << 16);
    pk.y = (unsigned)f2bf(r2) | ((unsigned)f2bf(r3) << 16);
    *(uint2*)&((ushort_t*)outv)[o] = pk;
  } else {
    float4 res; res.x = r0; res.y = r1; res.z = r2; res.w = r3;
    *(float4*)&((float*)outv)[o] = res;
  }
}

// ---------------- fused dual-list gather (user side; bf16 out) ----------------
template <int D, bool RELU>
__global__ __launch_bounds__(256) void k_gather2(const ushort_t* __restrict__ z1,
                                                 const ushort_t* __restrict__ z2,
                                                 const int* __restrict__ off1,
                                                 const int* __restrict__ adj1,
                                                 const int* __restrict__ off2,
                                                 const int* __restrict__ adj2,
                                                 const float* __restrict__ nd1,
                                                 const float* __restrict__ nd2,
                                                 const float* __restrict__ b1,
                                                 const float* __restrict__ b2,
                                                 ushort_t* __restrict__ out, int nv) {
  constexpr int LPN = D / 4;
  constexpr int NPB = 256 / LPN;
  int t = threadIdx.x;
  int slot = t / LPN, l = t % LPN;
  int v = blockIdx.x * NPB + slot;
  if (v >= nv) return;
  float4 A = {0.f, 0.f, 0.f, 0.f};
  float4 B = {0.f, 0.f, 0.f, 0.f};
  accum_list<D>(z1, adj1, off1[v], off1[v + 1], l, A);
  accum_list<D>(z2, adj2, off2[v], off2[v + 1], l, B);
  float n1 = nd1[v], n2 = nd2[v];
  float r0 = n1 * A.x + n2 * B.x + b1[4 * l]     + b2[4 * l];
  float r1 = n1 * A.y + n2 * B.y + b1[4 * l + 1] + b2[4 * l + 1];
  float r2 = n1 * A.z + n2 * B.z + b1[4 * l + 2] + b2[4 * l + 2];
  float r3 = n1 * A.w + n2 * B.w + b1[4 * l + 3] + b2[4 * l + 3];
  if constexpr (RELU) {
    r0 = fmaxf(r0, 0.f); r1 = fmaxf(r1, 0.f);
    r2 = fmaxf(r2, 0.f); r3 = fmaxf(r3, 0.f);
  }
  uint2 pk;
  pk.x = (unsigned)f2bf(r0) | ((unsigned)f2bf(r1) << 16);
  pk.y = (unsigned)f2bf(r2) | ((unsigned)f2bf(r3) << 16);
  *(uint2*)&out[(size_t)v * D + 4 * l] = pk;
}

// ---------------- CSR-ordered edge scoring: wave per user ----------------
// out[eid[e]] = dot64(up[u], ip[adj[e]])
__global__ __launch_bounds__(256) void k_score2(const float* __restrict__ up,
                                                const float* __restrict__ ip,
                                                const int* __restrict__ off,
                                                const int* __restrict__ adj,
                                                const int* __restrict__ eid,
                                                float* __restrict__ out, int nu) {
  int w = threadIdx.x >> 6, lane = threadIdx.x & 63;
  int u = blockIdx.x * 4 + w;
  if (u >= nu) return;
  float uc = up[(size_t)u * 64 + lane];
  int e0 = off[u], e1 = off[u + 1];
  int e = e0;
  for (; e + 2 <= e1; e += 2) {
    int sA = adj[e], sB = adj[e + 1];
    int idA = eid[e], idB = eid[e + 1];
    float pA = uc * ip[(size_t)sA * 64 + lane];
    float pB = uc * ip[(size_t)sB * 64 + lane];
#pragma unroll
    for (int d = 32; d >= 1; d >>= 1) {
      pA += __shfl_xor(pA, d, 64);
      pB += __shfl_xor(pB, d, 64);
    }
    if (lane == 0) { out[idA] = pA; out[idB] = pB; }
  }
  if (e < e1) {
    int s = adj[e], id = eid[e];
    float p = uc * ip[(size_t)s * 64 + lane];
#pragma unroll
    for (int d = 32; d >= 1; d >>= 1) p += __shfl_xor(p, d, 64);
    if (lane == 0) out[id] = p;
  }
}

// ---------------- host launch ----------------
extern "C" void kernel_launch(void* const* d_in, const int* in_sizes, int n_in,
                              void* d_out, int out_size, void* d_ws, size_t ws_size,
                              hipStream_t stream) {
  const float* emb_user = (const float*)d_in[0];
  const float* emb_d1   = (const float*)d_in[1];
  const float* emb_d2   = (const float*)d_in[2];
  const float* W_in     = (const float*)d_in[3];
  const float* b_in     = (const float*)d_in[4];
  const float* W_hid    = (const float*)d_in[5];
  const float* b_hid    = (const float*)d_in[6];
  const float* W_out    = (const float*)d_in[7];
  const float* b_out    = (const float*)d_in[8];
  const float* Wp_d1    = (const float*)d_in[9];
  const float* Wp_d2    = (const float*)d_in[10];
  const int* src_d1     = (const int*)d_in[11];
  const int* dst_d1     = (const int*)d_in[12];
  const int* src_d2     = (const int*)d_in[13];
  const int* dst_d2     = (const int*)d_in[14];
  float* out = (float*)d_out;

  char* p = (char*)d_ws;
  auto alloc = [&](size_t bytes) {
    void* r = (void*)p;
    p += (bytes + 15) & ~(size_t)15;
    return r;
  };
  // U stored bf16 (only ever feeds GEMMs, which bf16-cast A anyway -> zero extra error)
  ushort_t* bufU[2] = {(ushort_t*)alloc((size_t)NU * 128 * 2),
                       (ushort_t*)alloc((size_t)NU * 128 * 2)};
  // item buffers: bf16 [N][128] for layers 0-1, fp32 [N][64] for final (same byte size)
  void* bufI1 = alloc((size_t)N1 * 128 * 2);
  void* bufI2 = alloc((size_t)N2 * 128 * 2);
  ushort_t* m = (ushort_t*)alloc((size_t)(N1 + N2) * 128 * 2);  // z staging (also u1 fp32)
  float* nrm = (float*)alloc((size_t)TOTN * 4);
  int* deg = (int*)alloc((size_t)TOTN * 4);
  int* off = (int*)alloc((size_t)(TOTN + 4) * 4);
  int* cur = (int*)alloc((size_t)TOTN * 4);
  int* adj_s1 = (int*)alloc((size_t)E * 4);
  int* adj_d1 = (int*)alloc((size_t)E * 4);
  int* adj_s2 = (int*)alloc((size_t)E * 4);
  int* adj_d2 = (int*)alloc((size_t)E * 4);
  int* eid_s1 = (int*)alloc((size_t)E * 4);
  int* eid_s2 = (int*)alloc((size_t)E * 4);

  // ws guard: fail soft (absmax) instead of GPU fault if scratch too small
  if ((size_t)(p - (char*)d_ws) > ws_size) return;

  const float* nu1 = nrm;
  const float* ni1 = nrm + NU;
  const float* nu2 = nrm + NU + N1;
  const float* ni2 = nrm + 2 * NU + N1;
  const int* off_u1 = off;
  const int* off_i1 = off + NU + 1;
  const int* off_u2 = off + NU + N1 + 2;
  const int* off_i2 = off + 2 * NU + N1 + 3;

  // ---- graph preprocessing ----
  hipMemsetAsync(deg, 0, (size_t)TOTN * 4, stream);
  k_count<<<NCHUNKS * NPART, 256, 0, stream>>>(src_d1, dst_d1, src_d2, dst_d2, deg);
  k_norm<<<(TOTN + 255) / 256, 256, 0, stream>>>(deg, nrm);
  k_scan<<<4, 256, 0, stream>>>(deg, off, cur);
  k_fill<<<NCHUNKS * NPART, 256, 0, stream>>>(src_d1, dst_d1, src_d2, dst_d2, cur,
                                              adj_s1, adj_d1, adj_s2, adj_d2,
                                              eid_s1, eid_s2);

  ushort_t* mI1 = m;
  ushort_t* mI2 = m + (size_t)N1 * 128;
  ushort_t* mI1h = m;                       // 64-wide variants (L2)
  ushort_t* mI2h = m + (size_t)N1 * 64;
  ushort_t* mU = m;

  // ---- Layer 0 (A = fp32 embeddings, D=128) ----
  k_gemm<float, 128, 128, true><<<(N1 + 63) / 64, 256, 0, stream>>>(emb_d1, W_in + 1 * 128 * 128, mI1, N1, ni1);
  k_gemm<float, 128, 128, true><<<(N2 + 63) / 64, 256, 0, stream>>>(emb_d2, W_in + 3 * 128 * 128, mI2, N2, ni2);
  k_gather2<128, true><<<(NU + 7) / 8, 256, 0, stream>>>(
      mI1, mI2, off_u1, adj_s1, off_u2, adj_s2, nu1, nu2,
      b_in + 1 * 128, b_in + 3 * 128, bufU[0], NU);
  k_gemm<float, 128, 128, true><<<(NU + 63) / 64, 256, 0, stream>>>(emb_user, W_in + 0 * 128 * 128, mU, NU, nu1);
  k_gather<128, true, true><<<(N1 + 7) / 8, 256, 0, stream>>>(
      mU, off_i1, adj_d1, ni1, b_in + 0 * 128, bufI1, N1);
  k_gemm<float, 128, 128, true><<<(NU + 63) / 64, 256, 0, stream>>>(emb_user, W_in + 2 * 128 * 128, mU, NU, nu2);
  k_gather<128, true, true><<<(N2 + 7) / 8, 256, 0, stream>>>(
      mU, off_i2, adj_d2, ni2, b_in + 2 * 128, bufI2, N2);

  // ---- Layer 1 (A = bf16, D=128) ----
  k_gemm<ushort_t, 128, 128, true><<<(N1 + 63) / 64, 256, 0, stream>>>((ushort_t*)bufI1, W_hid + 1 * 128 * 128, mI1, N1, ni1);
  k_gemm<ushort_t, 128, 128, true><<<(N2 + 63) / 64, 256, 0, stream>>>((ushort_t*)bufI2, W_hid + 3 * 128 * 128, mI2, N2, ni2);
  k_gather2<128, true><<<(NU + 7) / 8, 256, 0, stream>>>(
      mI1, mI2, off_u1, adj_s1, off_u2, adj_s2, nu1, nu2,
      b_hid + 1 * 128, b_hid + 3 * 128, bufU[1], NU);
  k_gemm<ushort_t, 128, 128, true><<<(NU + 63) / 64, 256, 0, stream>>>(bufU[0], W_hid + 0 * 128 * 128, mU, NU, nu1);
  k_gather<128, true, true><<<(N1 + 7) / 8, 256, 0, stream>>>(
      mU, off_i1, adj_d1, ni1, b_hid + 0 * 128, bufI1, N1);
  k_gemm<ushort_t, 128, 128, true><<<(NU + 63) / 64, 256, 0, stream>>>(bufU[0], W_hid + 2 * 128 * 128, mU, NU, nu2);
  k_gather<128, true, true><<<(N2 + 7) / 8, 256, 0, stream>>>(
      mU, off_i2, adj_d2, ni2, b_hid + 2 * 128, bufI2, N2);

  // ---- Layer 2 (A = bf16, D=64; no relu; items to fp32 for scoring) ----
  k_gemm<ushort_t, 128, 64, true><<<(N1 + 63) / 64, 256, 0, stream>>>((ushort_t*)bufI1, W_out + 1 * 128 * 64, mI1h, N1, ni1);
  k_gemm<ushort_t, 128, 64, true><<<(N2 + 63) / 64, 256, 0, stream>>>((ushort_t*)bufI2, W_out + 3 * 128 * 64, mI2h, N2, ni2);
  k_gather2<64, false><<<(NU + 15) / 16, 256, 0, stream>>>(
      mI1h, mI2h, off_u1, adj_s1, off_u2, adj_s2, nu1, nu2,
      b_out + 1 * 64, b_out + 3 * 64, bufU[0], NU);
  k_gemm<ushort_t, 128, 64, true><<<(NU + 63) / 64, 256, 0, stream>>>(bufU[1], W_out + 0 * 128 * 64, mU, NU, nu1);
  k_gather<64, false, false><<<(N1 + 15) / 16, 256, 0, stream>>>(
      mU, off_i1, adj_d1, ni1, b_out + 0 * 64, bufI1, N1);
  k_gemm<ushort_t, 128, 64, true><<<(NU + 63) / 64, 256, 0, stream>>>(bufU[1], W_out + 2 * 128 * 64, mU, NU, nu2);
  k_gather<64, false, false><<<(N2 + 15) / 16, 256, 0, stream>>>(
      mU, off_i2, adj_d2, ni2, b_out + 2 * 64, bufI2, N2);

  // ---- projections (fp32 out) + CSR-ordered scoring ----
  float* u1 = (float*)m;          // 25.6 MB <= 30.7 MB
  float* u2 = (float*)bufU[1];    // 25.6 MB exact
  k_gemm<ushort_t, 64, 64, false><<<(NU + 63) / 64, 256, 0, stream>>>(bufU[0], Wp_d1, u1, NU, nullptr);
  k_gemm<ushort_t, 64, 64, false><<<(NU + 63) / 64, 256, 0, stream>>>(bufU[0], Wp_d2, u2, NU, nullptr);
  k_score2<<<(NU + 3) / 4, 256, 0, stream>>>(u1, (const float*)bufI1, off_u1, adj_s1, eid_s1, out, NU);
  k_score2<<<(NU + 3) / 4, 256, 0, stream>>>(u2, (const float*)bufI2, off_u2, adj_s2, eid_s2, out + E, NU);
}